// Round 1
// baseline (514.023 us; speedup 1.0000x reference)
//
#include <hip/hip_runtime.h>
#include <hip/hip_bf16.h>

// SplineCNN round 16: attack gemm_scatter (2x95us, top cost). Counters show
// nothing saturated (Mfma 4%, VALU 10%, HBM 35%, occ 44%) and round-14 dbuf
// was neutral -> limiter is the scattered 128B-granule write pattern
// (2.3 TB/s effective). New gemm16: block owns 16 rows x all 26 tiles,
// stages full 16x1600 bf16 row-panel in LDS (51KB, +8 ushort row pad),
// one barrier, then a single LINEAR 50KB uint4 burst to xWb (layout
// unchanged -> edge_csr untouched at its random-read ceiling). Scatter
// blocks moved to grid front. Dead x1f write dropped.

typedef short  bf16x8 __attribute__((ext_vector_type(8)));
typedef float  f32x4  __attribute__((ext_vector_type(4)));

__device__ __forceinline__ float bf2f(ushort u) {
    return __uint_as_float((uint)u << 16);
}
__device__ __forceinline__ ushort f2bf(float f) {   // round-to-nearest-even
    uint u = __float_as_uint(f);
    return (ushort)((u + 0x7FFF + ((u >> 16) & 1)) >> 16);
}

// ---------------- fused prep --------------------------------------------
// [0,nx): xb = bf16(x)
// [nx, nx+nw): WtA[tile][o][i] from W1|r1
// [+nw): WtB from W2|r2
// [+nfw): fwT[t][o][k] from fw[192][64]
// [+N): deg = 0
__global__ __launch_bounds__(256) void prep(
    const float* __restrict__ x, ushort* __restrict__ xb, int nx,
    const float* __restrict__ W1, const float* __restrict__ r1, ushort* __restrict__ WtA,
    const float* __restrict__ W2, const float* __restrict__ r2, ushort* __restrict__ WtB,
    const float* __restrict__ fw, ushort* __restrict__ fwT,
    int* __restrict__ deg, int N)
{
    const int nw = 26 * 4096, nfw = 3 * 4096;
    int idx = blockIdx.x * 256 + threadIdx.x;
    if (idx < nx) { xb[idx] = f2bf(x[idx]); return; }
    idx -= nx;
    if (idx < nw) {
        int tile = idx >> 12, rem = idx & 4095, o = rem >> 6, i = rem & 63;
        WtA[idx] = f2bf(tile < 25 ? W1[tile * 4096 + i * 64 + o] : r1[i * 64 + o]);
        return;
    }
    idx -= nw;
    if (idx < nw) {
        int tile = idx >> 12, rem = idx & 4095, o = rem >> 6, i = rem & 63;
        WtB[idx] = f2bf(tile < 25 ? W2[tile * 4096 + i * 64 + o] : r2[i * 64 + o]);
        return;
    }
    idx -= nw;
    if (idx < nfw) {
        int t = idx >> 12, rem = idx & 4095, o = rem >> 6, k = rem & 63;
        fwT[idx] = f2bf(fw[(t * 64 + k) * 64 + o]);
        return;
    }
    idx -= nfw;
    if (idx < N) deg[idx] = 0;
}

// ---------------- CSR build ---------------------------------------------
__global__ __launch_bounds__(256) void hist_deg(
    const int* __restrict__ ei, int* __restrict__ deg, int E)
{
    int e = blockIdx.x * 256 + threadIdx.x;
    if (e < E) atomicAdd(&deg[ei[E + e]], 1);
}

__global__ __launch_bounds__(1024) void scan_block(
    const int* __restrict__ deg, int* __restrict__ inc,
    int* __restrict__ partial, int N)
{
    __shared__ int s[1024];
    int i = blockIdx.x * 1024 + threadIdx.x;
    int v = (i < N) ? deg[i] : 0;
    s[threadIdx.x] = v;
    __syncthreads();
    for (int off = 1; off < 1024; off <<= 1) {
        int t = (threadIdx.x >= off) ? s[threadIdx.x - off] : 0;
        __syncthreads();
        s[threadIdx.x] += t;
        __syncthreads();
    }
    if (i < N) inc[i] = s[threadIdx.x];
    if (threadIdx.x == 1023) partial[blockIdx.x] = s[1023];
}

__global__ void scan_partial(int* __restrict__ partial, int nb)  // nb <= 64
{
    __shared__ int s[64];
    int t = threadIdx.x;
    int v = (t < nb) ? partial[t] : 0;
    s[t] = v;
    __syncthreads();
    for (int off = 1; off < 64; off <<= 1) {
        int x = (t >= off) ? s[t - off] : 0;
        __syncthreads();
        s[t] += x;
        __syncthreads();
    }
    if (t < nb) partial[t] = s[t] - v;   // exclusive block offsets
}

__global__ __launch_bounds__(1024) void scan_finalize(
    const int* __restrict__ deg, const int* __restrict__ inc,
    const int* __restrict__ partial, int* __restrict__ row_ptr,
    int* __restrict__ cursor, int N)
{
    int i = blockIdx.x * 1024 + threadIdx.x;
    if (i >= N) return;
    int v = inc[i] + partial[blockIdx.x];
    row_ptr[i + 1] = v;
    cursor[i] = v - deg[i];
    if (i == 0) row_ptr[0] = 0;
}

// ---------------- row-panel MFMA GEMM + csr_scatter ---------------------
// bx < scb: scatter blocks (layer 1 only), flat edge id = bx*256+tid.
// bx >= scb: gemm — block owns rows m0..m0+15, loops ALL 26 tiles
// (waves stripe tiles t ≡ wave mod 4). bf16 outputs staged in a 16x1600
// LDS panel (row stride 1608 ushort: 16B-aligned rows, 2-way banks=free),
// one barrier, then one linear 50KB uint4 burst. Root tile (25) goes
// fp32 direct to xRoot as before. xWb layout [m][tile][ch] UNCHANGED.
__global__ __launch_bounds__(256) void gemm16_scatter(
    const ushort* __restrict__ A, const ushort* __restrict__ Wt,
    ushort* __restrict__ xWb, float* __restrict__ xRoot, int scb,
    const int* __restrict__ ei, const float* __restrict__ attr,
    int* __restrict__ cursor, int4* __restrict__ epack, int E)
{
    __shared__ ushort sT[16 * 1608];
    const int tid = threadIdx.x;
    const int bx = blockIdx.x;

    if (bx < scb) {                 // ---- scatter path (layer 1 only) ----
        if (!ei) return;
        int e = bx * 256 + tid;
        if (e >= E) return;
        int src = ei[e], dst = ei[E + e];
        float u = attr[2 * e] * 4.f;
        float v = attr[2 * e + 1] * 4.f;
        float lu = floorf(u), lv = floorf(v);
        float fu = u - lu, fv = v - lv;
        int iu = (int)lu;  iu = iu < 0 ? 0 : (iu > 4 ? 4 : iu);
        int iv = (int)lv;  iv = iv < 0 ? 0 : (iv > 4 ? 4 : iv);
        int iu1 = iu + 1 > 4 ? 4 : iu + 1;
        int iv1 = iv + 1 > 4 ? 4 : iv + 1;
        uint slots = (uint)(iu + 5 * iv) | ((uint)(iu + 5 * iv1) << 8) |
                     ((uint)(iu1 + 5 * iv) << 16) | ((uint)(iu1 + 5 * iv1) << 24);
        uint wlo = (uint)f2bf((1.f - fu) * (1.f - fv)) | ((uint)f2bf((1.f - fu) * fv) << 16);
        uint whi = (uint)f2bf(fu * (1.f - fv)) | ((uint)f2bf(fu * fv) << 16);
        int pos = atomicAdd(&cursor[dst], 1);
        epack[pos] = make_int4(src * 3200, (int)slots, (int)wlo, (int)whi);
        return;
    }

    // ---- gemm path ----
    const int wave = tid >> 6;
    const int lane = tid & 63;
    const int l16 = lane & 15;
    const int half = lane >> 4;                 // 0..3
    const int m0 = (bx - scb) * 16;

    // A-fragments for the block's 16 rows (loaded once, shared by all tiles)
    const ushort* arow = A + (size_t)(m0 + l16) * 64;
    const bf16x8 a0 = *(const bf16x8*)(arow + half * 8);
    const bf16x8 a1 = *(const bf16x8*)(arow + 32 + half * 8);

    for (int t = wave; t < 26; t += 4) {        // waves stripe the tiles
        const ushort* btile = Wt + (size_t)t * 4096;
        f32x4 acc[4];
        #pragma unroll
        for (int s = 0; s < 4; ++s) {
            const ushort* brow = btile + (size_t)(s * 16 + l16) * 64;
            bf16x8 b0 = *(const bf16x8*)(brow + half * 8);
            bf16x8 b1 = *(const bf16x8*)(brow + 32 + half * 8);
            acc[s] = (f32x4){0.f, 0.f, 0.f, 0.f};
            acc[s] = __builtin_amdgcn_mfma_f32_16x16x32_bf16(a0, b0, acc[s], 0, 0, 0);
            acc[s] = __builtin_amdgcn_mfma_f32_16x16x32_bf16(a1, b1, acc[s], 0, 0, 0);
        }
        if (t == 25) {   // root tile -> fp32 xRoot (padded ws, no guard)
            #pragma unroll
            for (int s = 0; s < 4; ++s)
                #pragma unroll
                for (int r = 0; r < 4; ++r)
                    xRoot[(size_t)(m0 + half * 4 + r) * 64 + s * 16 + l16] = acc[s][r];
        } else {
            #pragma unroll
            for (int s = 0; s < 4; ++s)
                #pragma unroll
                for (int r = 0; r < 4; ++r)
                    sT[(half * 4 + r) * 1608 + t * 64 + s * 16 + l16] = f2bf(acc[s][r]);
        }
    }

    __syncthreads();
    // linear 50KB burst: global region [m0*1600, (m0+16)*1600) is contiguous
    const size_t gbase = (size_t)m0 * 1600;
    for (int q = tid; q < 3200; q += 256) {     // 3200 uint4 = 16 rows x 200
        int row = q / 200;
        int c = q - row * 200;
        uint4 v = *(const uint4*)&sT[row * 1608 + c * 8];
        *(uint4*)(xWb + gbase + (size_t)row * 1600 + (size_t)c * 8) = v;
    }
}

// ---------------- edge pass: wave/dst, pipelined scalarized stream ------
__device__ __forceinline__ void gather4(
    const char* __restrict__ xwb, int lane, int rb, uint slots, ushort g[4])
{
    g[0] = *((const ushort*)(xwb + rb + ((slots & 255u) << 7)) + lane);
    g[1] = *((const ushort*)(xwb + rb + (((slots >> 8) & 255u) << 7)) + lane);
    g[2] = *((const ushort*)(xwb + rb + (((slots >> 16) & 255u) << 7)) + lane);
    g[3] = *((const ushort*)(xwb + rb + ((slots >> 24) << 7)) + lane);
}

__device__ __forceinline__ float consume4(const int4 d, const ushort g[4])
{
    float m = __uint_as_float((uint)d.z << 16) * bf2f(g[0]);
    m = fmaf(__uint_as_float((uint)d.z & 0xffff0000u), bf2f(g[1]), m);
    m = fmaf(__uint_as_float((uint)d.w << 16), bf2f(g[2]), m);
    m = fmaf(__uint_as_float((uint)d.w & 0xffff0000u), bf2f(g[3]), m);
    return m;
}

__global__ __launch_bounds__(256) void edge_csr(
    const ushort* __restrict__ xWb, const int* __restrict__ row_ptr,
    const int4* __restrict__ epack, const float* __restrict__ xRoot,
    const float* __restrict__ bias, float* __restrict__ outf,
    ushort* __restrict__ outb, int N)
{
    const int wv = __builtin_amdgcn_readfirstlane(threadIdx.x >> 6);
    const int d = blockIdx.x * 4 + wv;
    const int lane = threadIdx.x & 63;
    if (d >= N) return;
    const int e0 = __builtin_amdgcn_readfirstlane(row_ptr[d]);
    const int e1 = __builtin_amdgcn_readfirstlane(row_ptr[d + 1]);
    const char* xwb = (const char*)xWb;

    float vmax = -__builtin_inff();
    int e = e0;
    const int pairs = (e1 - e0) >> 1;
    if (pairs > 0) {
        int4 dA = epack[e], dB = epack[e + 1];
        ushort gA[4], gB[4];
        gather4(xwb, lane, dA.x, (uint)dA.y, gA);
        gather4(xwb, lane, dB.x, (uint)dB.y, gB);
        for (int p = 1; p < pairs; ++p) {
            int4 nA = epack[e + 2 * p], nB = epack[e + 2 * p + 1];
            ushort hA[4], hB[4];
            gather4(xwb, lane, nA.x, (uint)nA.y, hA);
            gather4(xwb, lane, nB.x, (uint)nB.y, hB);
            vmax = fmaxf(vmax, fmaxf(consume4(dA, gA), consume4(dB, gB)));
            #pragma unroll
            for (int i = 0; i < 4; ++i) { gA[i] = hA[i]; gB[i] = hB[i]; }
            dA = nA; dB = nB;
        }
        vmax = fmaxf(vmax, fmaxf(consume4(dA, gA), consume4(dB, gB)));
        e += pairs * 2;
    }
    if (e < e1) {   // odd remainder
        int4 dA = epack[e];
        ushort gA[4];
        gather4(xwb, lane, dA.x, (uint)dA.y, gA);
        vmax = fmaxf(vmax, consume4(dA, gA));
    }
    if (e1 == e0) vmax = 0.f;          // segment_max(-inf) -> 0
    float val = vmax + xRoot[(size_t)d * 64 + lane] + bias[lane];
    val = fmaxf(val, 0.f);
    if (outf) outf[(size_t)d * 64 + lane] = val;
    if (outb) outb[(size_t)d * 64 + lane] = f2bf(val);
}

// ---------------- final: out = [xb|x1b|x2b] @ fwT + fb (bf16 MFMA) ------
__global__ __launch_bounds__(256) void final_mfma(
    const ushort* __restrict__ xb, const ushort* __restrict__ x1b,
    const ushort* __restrict__ x2b, const ushort* __restrict__ fwT,
    const float* __restrict__ fb, float* __restrict__ out, int M)
{
    const int wave = threadIdx.x >> 6;
    const int lane = threadIdx.x & 63;
    const int l16 = lane & 15;
    const int half = lane >> 4;
    const int m_base = blockIdx.x * 64 + wave * 16;
    const ushort* srcs[3] = {xb, x1b, x2b};

    f32x4 acc[4];
    #pragma unroll
    for (int s = 0; s < 4; ++s) acc[s] = (f32x4){0.f, 0.f, 0.f, 0.f};

    #pragma unroll
    for (int t = 0; t < 3; ++t) {
        const ushort* arow = srcs[t] + (size_t)(m_base + l16) * 64;
        bf16x8 a0 = *(const bf16x8*)(arow + half * 8);
        bf16x8 a1 = *(const bf16x8*)(arow + 32 + half * 8);
        const ushort* btile = fwT + (size_t)t * 4096;
        #pragma unroll
        for (int s = 0; s < 4; ++s) {
            const ushort* brow = btile + (size_t)(s * 16 + l16) * 64;
            bf16x8 b0 = *(const bf16x8*)(brow + half * 8);
            bf16x8 b1 = *(const bf16x8*)(brow + 32 + half * 8);
            acc[s] = __builtin_amdgcn_mfma_f32_16x16x32_bf16(a0, b0, acc[s], 0, 0, 0);
            acc[s] = __builtin_amdgcn_mfma_f32_16x16x32_bf16(a1, b1, acc[s], 0, 0, 0);
        }
    }

    #pragma unroll
    for (int s = 0; s < 4; ++s) {
        int o = s * 16 + l16;
        float b = fb[o];
        #pragma unroll
        for (int r = 0; r < 4; ++r) {
            int m = m_base + half * 4 + r;
            if (m < M) out[(size_t)m * 64 + o] = acc[s][r] + b;
        }
    }
}

extern "C" void kernel_launch(void* const* d_in, const int* in_sizes, int n_in,
                              void* d_out, int out_size, void* d_ws, size_t ws_size,
                              hipStream_t stream)
{
    const float* x    = (const float*)d_in[0];
    const int*   ei   = (const int*)d_in[1];
    const float* attr = (const float*)d_in[2];
    const float* W1   = (const float*)d_in[3];
    const float* r1   = (const float*)d_in[4];
    const float* b1   = (const float*)d_in[5];
    const float* W2   = (const float*)d_in[6];
    const float* r2   = (const float*)d_in[7];
    const float* b2   = (const float*)d_in[8];
    const float* fw   = (const float*)d_in[9];
    const float* fb   = (const float*)d_in[10];
    float* out = (float*)d_out;

    const int N = in_sizes[0] / 64;
    const int E = in_sizes[1] / 2;
    const int mtiles = (N + 63) / 64;
    const int Npad = mtiles * 64;

    // workspace carve (~215 MB; ws_size >= 358 MB per round-2 evidence)
    char* p = (char*)d_ws;
    auto alloc = [&](size_t bytes) { void* q = p; p += (bytes + 255) & ~(size_t)255; return q; };
    int4*   epack  = (int4*)alloc((size_t)E * 16);
    float*  xRoot  = (float*)alloc((size_t)Npad * 64 * 4);
    ushort* xWb    = (ushort*)alloc((size_t)Npad * 1600 * 2);
    ushort* xb     = (ushort*)alloc((size_t)Npad * 64 * 2);
    ushort* x1b    = (ushort*)alloc((size_t)Npad * 64 * 2);
    ushort* x2b    = (ushort*)alloc((size_t)Npad * 64 * 2);
    ushort* WtA    = (ushort*)alloc((size_t)26 * 4096 * 2);
    ushort* WtB    = (ushort*)alloc((size_t)26 * 4096 * 2);
    ushort* fwT    = (ushort*)alloc((size_t)3 * 4096 * 2);
    int*    deg    = (int*)alloc((size_t)N * 4);
    int*    cursor = (int*)alloc((size_t)N * 4);
    int*    rowp   = (int*)alloc((size_t)(N + 1) * 4);
    int*    tmpinc = (int*)alloc((size_t)N * 4);
    int*    part   = (int*)alloc(64 * 4);

    const int nb = (N + 1023) / 1024;   // <= 64 for N <= 65536

    // fused prep: xb, WtA, WtB, fwT, zero deg
    const int nprep = N * 64 + 2 * 26 * 4096 + 3 * 4096 + N;
    prep<<<(nprep + 255) / 256, 256, 0, stream>>>(
        x, xb, N * 64, W1, r1, WtA, W2, r2, WtB, fw, fwT, deg, N);

    // CSR scan chain (scatter fused into layer-1 gemm)
    hist_deg<<<(E + 255) / 256, 256, 0, stream>>>(ei, deg, E);
    scan_block<<<nb, 1024, 0, stream>>>(deg, tmpinc, part, N);
    scan_partial<<<1, 64, 0, stream>>>(part, nb);
    scan_finalize<<<nb, 1024, 0, stream>>>(deg, tmpinc, part, rowp, cursor, N);

    const int nmb = mtiles * 4;               // Npad/16 row-panel blocks
    const int sc_blocks = (E + 255) / 256;    // scatter blocks (front of grid)

    // layer 1: scatter (front) + row-panel gemm
    gemm16_scatter<<<sc_blocks + nmb, 256, 0, stream>>>(
        xb, WtA, xWb, xRoot, sc_blocks, ei, attr, cursor, epack, E);
    edge_csr<<<(N + 3) / 4, 256, 0, stream>>>(xWb, rowp, epack, xRoot, b1, nullptr, x1b, N);

    // layer 2: gemm only
    gemm16_scatter<<<nmb, 256, 0, stream>>>(
        x1b, WtB, xWb, xRoot, 0, nullptr, nullptr, nullptr, nullptr, E);
    edge_csr<<<(N + 3) / 4, 256, 0, stream>>>(xWb, rowp, epack, xRoot, b2, nullptr, x2b, N);

    // final: bf16 MFMA, fp32 out + fb
    final_mfma<<<mtiles, 256, 0, stream>>>(xb, x1b, x2b, fwT, fb, out, N);
}

// Round 2
// 406.925 us; speedup vs baseline: 1.2632x; 1.2632x over previous
//
#include <hip/hip_runtime.h>
#include <hip/hip_bf16.h>

// SplineCNN round 17: revert round-16 (row-panel gemm regressed 95->153us:
// WRITE_SIZE identical 219MB both rounds => no write amplification ever;
// limiter is store RATE. Round-16 lost on occupancy, not addressing).
// Back to round-13 structure, but BARRIER-FREE gemm: __syncthreads compiles
// to s_waitcnt vmcnt(0)+s_barrier which drains ALL outstanding xWb stores
// 16x per block (convoy; explains Mfma 4%/VALU 10%/HBM 35%/nothing
// saturated). Fix: per-wave private 16x72 LDS slice -> each wave stages and
// stores its OWN 16 rows; all LDS deps are same-wave in-order lgkm waits;
// ZERO barriers. A-frags for it+1 prefetched before it's stores so MFMA
// waits vmcnt(2), never vmcnt(0): stores stay in flight across iterations.
// Dead x1f write dropped (layer2/final read x1b only).

typedef short  bf16x8 __attribute__((ext_vector_type(8)));
typedef float  f32x4  __attribute__((ext_vector_type(4)));

__device__ __forceinline__ float bf2f(ushort u) {
    return __uint_as_float((uint)u << 16);
}
__device__ __forceinline__ ushort f2bf(float f) {   // round-to-nearest-even
    uint u = __float_as_uint(f);
    return (ushort)((u + 0x7FFF + ((u >> 16) & 1)) >> 16);
}

// ---------------- fused prep --------------------------------------------
__global__ __launch_bounds__(256) void prep(
    const float* __restrict__ x, ushort* __restrict__ xb, int nx,
    const float* __restrict__ W1, const float* __restrict__ r1, ushort* __restrict__ WtA,
    const float* __restrict__ W2, const float* __restrict__ r2, ushort* __restrict__ WtB,
    const float* __restrict__ fw, ushort* __restrict__ fwT,
    int* __restrict__ deg, int N)
{
    const int nw = 26 * 4096, nfw = 3 * 4096;
    int idx = blockIdx.x * 256 + threadIdx.x;
    if (idx < nx) { xb[idx] = f2bf(x[idx]); return; }
    idx -= nx;
    if (idx < nw) {
        int tile = idx >> 12, rem = idx & 4095, o = rem >> 6, i = rem & 63;
        WtA[idx] = f2bf(tile < 25 ? W1[tile * 4096 + i * 64 + o] : r1[i * 64 + o]);
        return;
    }
    idx -= nw;
    if (idx < nw) {
        int tile = idx >> 12, rem = idx & 4095, o = rem >> 6, i = rem & 63;
        WtB[idx] = f2bf(tile < 25 ? W2[tile * 4096 + i * 64 + o] : r2[i * 64 + o]);
        return;
    }
    idx -= nw;
    if (idx < nfw) {
        int t = idx >> 12, rem = idx & 4095, o = rem >> 6, k = rem & 63;
        fwT[idx] = f2bf(fw[(t * 64 + k) * 64 + o]);
        return;
    }
    idx -= nfw;
    if (idx < N) deg[idx] = 0;
}

// ---------------- CSR build ---------------------------------------------
__global__ __launch_bounds__(256) void hist_deg(
    const int* __restrict__ ei, int* __restrict__ deg, int E)
{
    int e = blockIdx.x * 256 + threadIdx.x;
    if (e < E) atomicAdd(&deg[ei[E + e]], 1);
}

__global__ __launch_bounds__(1024) void scan_block(
    const int* __restrict__ deg, int* __restrict__ inc,
    int* __restrict__ partial, int N)
{
    __shared__ int s[1024];
    int i = blockIdx.x * 1024 + threadIdx.x;
    int v = (i < N) ? deg[i] : 0;
    s[threadIdx.x] = v;
    __syncthreads();
    for (int off = 1; off < 1024; off <<= 1) {
        int t = (threadIdx.x >= off) ? s[threadIdx.x - off] : 0;
        __syncthreads();
        s[threadIdx.x] += t;
        __syncthreads();
    }
    if (i < N) inc[i] = s[threadIdx.x];
    if (threadIdx.x == 1023) partial[blockIdx.x] = s[1023];
}

__global__ void scan_partial(int* __restrict__ partial, int nb)  // nb <= 64
{
    __shared__ int s[64];
    int t = threadIdx.x;
    int v = (t < nb) ? partial[t] : 0;
    s[t] = v;
    __syncthreads();
    for (int off = 1; off < 64; off <<= 1) {
        int x = (t >= off) ? s[t - off] : 0;
        __syncthreads();
        s[t] += x;
        __syncthreads();
    }
    if (t < nb) partial[t] = s[t] - v;   // exclusive block offsets
}

__global__ __launch_bounds__(1024) void scan_finalize(
    const int* __restrict__ deg, const int* __restrict__ inc,
    const int* __restrict__ partial, int* __restrict__ row_ptr,
    int* __restrict__ cursor, int N)
{
    int i = blockIdx.x * 1024 + threadIdx.x;
    if (i >= N) return;
    int v = inc[i] + partial[blockIdx.x];
    row_ptr[i + 1] = v;
    cursor[i] = v - deg[i];
    if (i == 0) row_ptr[0] = 0;
}

// ---------------- fused MFMA GEMM + csr_scatter (barrier-free) ----------
// bx < 26: xW GEMM, 8 M-sub-tiles/block. Each wave owns rows
// m_base..m_base+15 of the current sub-tile and a PRIVATE 16x72 LDS slice:
// stage bf16 fragment -> same-wave ds_read -> coalesced uint4 stores.
// No __syncthreads anywhere => global stores are never vmcnt(0)-drained.
// A-frags for it+1 issued before it's stores => MFMA waits vmcnt(2).
// bx >= 26: csr_scatter blocks, flat id (bx-26)*gridDim.y + by.
__global__ __launch_bounds__(256) void gemm_scatter(
    const ushort* __restrict__ A, const ushort* __restrict__ Wt,
    ushort* __restrict__ xWb, float* __restrict__ xRoot, int mtiles,
    const int* __restrict__ ei, const float* __restrict__ attr,
    int* __restrict__ cursor, int4* __restrict__ epack, int E)
{
    __shared__ ushort Cs[4][16][72];   // per-wave slice, 144B rows
    const int bx = blockIdx.x;

    if (bx >= 26) {                 // ---- scatter path (layer 1 only) ----
        if (!ei) return;
        int e = ((bx - 26) * gridDim.y + blockIdx.y) * 256 + threadIdx.x;
        if (e >= E) return;
        int src = ei[e], dst = ei[E + e];
        float u = attr[2 * e] * 4.f;
        float v = attr[2 * e + 1] * 4.f;
        float lu = floorf(u), lv = floorf(v);
        float fu = u - lu, fv = v - lv;
        int iu = (int)lu;  iu = iu < 0 ? 0 : (iu > 4 ? 4 : iu);
        int iv = (int)lv;  iv = iv < 0 ? 0 : (iv > 4 ? 4 : iv);
        int iu1 = iu + 1 > 4 ? 4 : iu + 1;
        int iv1 = iv + 1 > 4 ? 4 : iv + 1;
        uint slots = (uint)(iu + 5 * iv) | ((uint)(iu + 5 * iv1) << 8) |
                     ((uint)(iu1 + 5 * iv) << 16) | ((uint)(iu1 + 5 * iv1) << 24);
        uint wlo = (uint)f2bf((1.f - fu) * (1.f - fv)) | ((uint)f2bf((1.f - fu) * fv) << 16);
        uint whi = (uint)f2bf(fu * (1.f - fv)) | ((uint)f2bf(fu * fv) << 16);
        int pos = atomicAdd(&cursor[dst], 1);
        epack[pos] = make_int4(src * 3200, (int)slots, (int)wlo, (int)whi);
        return;
    }

    // ---- gemm path ----
    const int wave = threadIdx.x >> 6;
    const int lane = threadIdx.x & 63;
    const int l16 = lane & 15;
    const int half = lane >> 4;                 // 0..3
    ushort (*cw)[72] = Cs[wave];

    const ushort* btile = Wt + (size_t)bx * 4096;
    bf16x8 b0[4], b1[4];
    #pragma unroll
    for (int s = 0; s < 4; ++s) {
        const ushort* brow = btile + (size_t)(s * 16 + l16) * 64;
        b0[s] = *(const bf16x8*)(brow + half * 8);
        b1[s] = *(const bf16x8*)(brow + 32 + half * 8);
    }

    const int mt_base = blockIdx.y * 8;
    const int nit = (mtiles - mt_base) < 8 ? (mtiles - mt_base) : 8;

    // prefetch A for it=0
    const ushort* arow0 = A + (size_t)(mt_base * 64 + wave * 16 + l16) * 64;
    bf16x8 a0 = *(const bf16x8*)(arow0 + half * 8);
    bf16x8 a1 = *(const bf16x8*)(arow0 + 32 + half * 8);

    for (int it = 0; it < nit; ++it) {
        const int m0 = (mt_base + it) * 64;
        const int m_base = m0 + wave * 16;

        // issue next iteration's A loads BEFORE this iteration's stores
        bf16x8 na0, na1;
        if (it + 1 < nit) {
            const ushort* arow = A + (size_t)(m_base + 64 + l16) * 64;
            na0 = *(const bf16x8*)(arow + half * 8);
            na1 = *(const bf16x8*)(arow + 32 + half * 8);
        }

        f32x4 acc[4];
        #pragma unroll
        for (int s = 0; s < 4; ++s) {
            acc[s] = (f32x4){0.f, 0.f, 0.f, 0.f};
            acc[s] = __builtin_amdgcn_mfma_f32_16x16x32_bf16(a0, b0[s], acc[s], 0, 0, 0);
            acc[s] = __builtin_amdgcn_mfma_f32_16x16x32_bf16(a1, b1[s], acc[s], 0, 0, 0);
        }

        if (bx == 25) {   // root tile -> fp32 xRoot (padded ws, no guard)
            #pragma unroll
            for (int s = 0; s < 4; ++s)
                #pragma unroll
                for (int r = 0; r < 4; ++r)
                    xRoot[(size_t)(m_base + half * 4 + r) * 64 + s * 16 + l16] = acc[s][r];
        } else {
            // per-wave stage: bf16 fragment -> LDS slice (same-wave only)
            #pragma unroll
            for (int s = 0; s < 4; ++s)
                #pragma unroll
                for (int r = 0; r < 4; ++r)
                    cw[half * 4 + r][s * 16 + l16] = f2bf(acc[s][r]);
            // same-wave readback -> coalesced uint4 stores of our 16 rows
            #pragma unroll
            for (int i2 = 0; i2 < 2; ++i2) {
                int idx = i2 * 64 + lane;
                int row = idx >> 3, seg = idx & 7;
                uint4 v = *(const uint4*)&cw[row][seg * 8];
                *(uint4*)(xWb + (size_t)(m_base + row) * 1600 + bx * 64 + seg * 8) = v;
            }
        }
        a0 = na0; a1 = na1;
    }
}

// ---------------- edge pass: wave/dst, pipelined scalarized stream ------
__device__ __forceinline__ void gather4(
    const char* __restrict__ xwb, int lane, int rb, uint slots, ushort g[4])
{
    g[0] = *((const ushort*)(xwb + rb + ((slots & 255u) << 7)) + lane);
    g[1] = *((const ushort*)(xwb + rb + (((slots >> 8) & 255u) << 7)) + lane);
    g[2] = *((const ushort*)(xwb + rb + (((slots >> 16) & 255u) << 7)) + lane);
    g[3] = *((const ushort*)(xwb + rb + ((slots >> 24) << 7)) + lane);
}

__device__ __forceinline__ float consume4(const int4 d, const ushort g[4])
{
    float m = __uint_as_float((uint)d.z << 16) * bf2f(g[0]);
    m = fmaf(__uint_as_float((uint)d.z & 0xffff0000u), bf2f(g[1]), m);
    m = fmaf(__uint_as_float((uint)d.w << 16), bf2f(g[2]), m);
    m = fmaf(__uint_as_float((uint)d.w & 0xffff0000u), bf2f(g[3]), m);
    return m;
}

__global__ __launch_bounds__(256) void edge_csr(
    const ushort* __restrict__ xWb, const int* __restrict__ row_ptr,
    const int4* __restrict__ epack, const float* __restrict__ xRoot,
    const float* __restrict__ bias, float* __restrict__ outf,
    ushort* __restrict__ outb, int N)
{
    const int wv = __builtin_amdgcn_readfirstlane(threadIdx.x >> 6);
    const int d = blockIdx.x * 4 + wv;
    const int lane = threadIdx.x & 63;
    if (d >= N) return;
    const int e0 = __builtin_amdgcn_readfirstlane(row_ptr[d]);
    const int e1 = __builtin_amdgcn_readfirstlane(row_ptr[d + 1]);
    const char* xwb = (const char*)xWb;

    float vmax = -__builtin_inff();
    int e = e0;
    const int pairs = (e1 - e0) >> 1;
    if (pairs > 0) {
        int4 dA = epack[e], dB = epack[e + 1];
        ushort gA[4], gB[4];
        gather4(xwb, lane, dA.x, (uint)dA.y, gA);
        gather4(xwb, lane, dB.x, (uint)dB.y, gB);
        for (int p = 1; p < pairs; ++p) {
            int4 nA = epack[e + 2 * p], nB = epack[e + 2 * p + 1];
            ushort hA[4], hB[4];
            gather4(xwb, lane, nA.x, (uint)nA.y, hA);
            gather4(xwb, lane, nB.x, (uint)nB.y, hB);
            vmax = fmaxf(vmax, fmaxf(consume4(dA, gA), consume4(dB, gB)));
            #pragma unroll
            for (int i = 0; i < 4; ++i) { gA[i] = hA[i]; gB[i] = hB[i]; }
            dA = nA; dB = nB;
        }
        vmax = fmaxf(vmax, fmaxf(consume4(dA, gA), consume4(dB, gB)));
        e += pairs * 2;
    }
    if (e < e1) {   // odd remainder
        int4 dA = epack[e];
        ushort gA[4];
        gather4(xwb, lane, dA.x, (uint)dA.y, gA);
        vmax = fmaxf(vmax, consume4(dA, gA));
    }
    if (e1 == e0) vmax = 0.f;          // segment_max(-inf) -> 0
    float val = vmax + xRoot[(size_t)d * 64 + lane] + bias[lane];
    val = fmaxf(val, 0.f);
    if (outf) outf[(size_t)d * 64 + lane] = val;
    if (outb) outb[(size_t)d * 64 + lane] = f2bf(val);
}

// ---------------- final: out = [xb|x1b|x2b] @ fwT + fb (bf16 MFMA) ------
__global__ __launch_bounds__(256) void final_mfma(
    const ushort* __restrict__ xb, const ushort* __restrict__ x1b,
    const ushort* __restrict__ x2b, const ushort* __restrict__ fwT,
    const float* __restrict__ fb, float* __restrict__ out, int M)
{
    const int wave = threadIdx.x >> 6;
    const int lane = threadIdx.x & 63;
    const int l16 = lane & 15;
    const int half = lane >> 4;
    const int m_base = blockIdx.x * 64 + wave * 16;
    const ushort* srcs[3] = {xb, x1b, x2b};

    f32x4 acc[4];
    #pragma unroll
    for (int s = 0; s < 4; ++s) acc[s] = (f32x4){0.f, 0.f, 0.f, 0.f};

    #pragma unroll
    for (int t = 0; t < 3; ++t) {
        const ushort* arow = srcs[t] + (size_t)(m_base + l16) * 64;
        bf16x8 a0 = *(const bf16x8*)(arow + half * 8);
        bf16x8 a1 = *(const bf16x8*)(arow + 32 + half * 8);
        const ushort* btile = fwT + (size_t)t * 4096;
        #pragma unroll
        for (int s = 0; s < 4; ++s) {
            const ushort* brow = btile + (size_t)(s * 16 + l16) * 64;
            bf16x8 b0 = *(const bf16x8*)(brow + half * 8);
            bf16x8 b1 = *(const bf16x8*)(brow + 32 + half * 8);
            acc[s] = __builtin_amdgcn_mfma_f32_16x16x32_bf16(a0, b0, acc[s], 0, 0, 0);
            acc[s] = __builtin_amdgcn_mfma_f32_16x16x32_bf16(a1, b1, acc[s], 0, 0, 0);
        }
    }

    #pragma unroll
    for (int s = 0; s < 4; ++s) {
        int o = s * 16 + l16;
        float b = fb[o];
        #pragma unroll
        for (int r = 0; r < 4; ++r) {
            int m = m_base + half * 4 + r;
            if (m < M) out[(size_t)m * 64 + o] = acc[s][r] + b;
        }
    }
}

extern "C" void kernel_launch(void* const* d_in, const int* in_sizes, int n_in,
                              void* d_out, int out_size, void* d_ws, size_t ws_size,
                              hipStream_t stream)
{
    const float* x    = (const float*)d_in[0];
    const int*   ei   = (const int*)d_in[1];
    const float* attr = (const float*)d_in[2];
    const float* W1   = (const float*)d_in[3];
    const float* r1   = (const float*)d_in[4];
    const float* b1   = (const float*)d_in[5];
    const float* W2   = (const float*)d_in[6];
    const float* r2   = (const float*)d_in[7];
    const float* b2   = (const float*)d_in[8];
    const float* fw   = (const float*)d_in[9];
    const float* fb   = (const float*)d_in[10];
    float* out = (float*)d_out;

    const int N = in_sizes[0] / 64;
    const int E = in_sizes[1] / 2;
    const int mtiles = (N + 63) / 64;
    const int Npad = mtiles * 64;

    // workspace carve (~215 MB; ws_size >= 358 MB per round-2 evidence)
    char* p = (char*)d_ws;
    auto alloc = [&](size_t bytes) { void* q = p; p += (bytes + 255) & ~(size_t)255; return q; };
    int4*   epack  = (int4*)alloc((size_t)E * 16);
    float*  xRoot  = (float*)alloc((size_t)Npad * 64 * 4);
    ushort* xWb    = (ushort*)alloc((size_t)Npad * 1600 * 2);
    ushort* xb     = (ushort*)alloc((size_t)Npad * 64 * 2);
    ushort* x1b    = (ushort*)alloc((size_t)Npad * 64 * 2);
    ushort* x2b    = (ushort*)alloc((size_t)Npad * 64 * 2);
    ushort* WtA    = (ushort*)alloc((size_t)26 * 4096 * 2);
    ushort* WtB    = (ushort*)alloc((size_t)26 * 4096 * 2);
    ushort* fwT    = (ushort*)alloc((size_t)3 * 4096 * 2);
    int*    deg    = (int*)alloc((size_t)N * 4);
    int*    cursor = (int*)alloc((size_t)N * 4);
    int*    rowp   = (int*)alloc((size_t)(N + 1) * 4);
    int*    tmpinc = (int*)alloc((size_t)N * 4);
    int*    part   = (int*)alloc(64 * 4);

    const int nb = (N + 1023) / 1024;   // <= 64 for N <= 65536

    // fused prep: xb, WtA, WtB, fwT, zero deg
    const int nprep = N * 64 + 2 * 26 * 4096 + 3 * 4096 + N;
    prep<<<(nprep + 255) / 256, 256, 0, stream>>>(
        x, xb, N * 64, W1, r1, WtA, W2, r2, WtB, fw, fwT, deg, N);

    // CSR scan chain (scatter fused into layer-1 gemm)
    hist_deg<<<(E + 255) / 256, 256, 0, stream>>>(ei, deg, E);
    scan_block<<<nb, 1024, 0, stream>>>(deg, tmpinc, part, N);
    scan_partial<<<1, 64, 0, stream>>>(part, nb);
    scan_finalize<<<nb, 1024, 0, stream>>>(deg, tmpinc, part, rowp, cursor, N);

    const int gy = (mtiles + 7) / 8;
    const int sc_blocks = (E + 255) / 256;
    const int sc_cols = (sc_blocks + gy - 1) / gy;

    // layer 1: gemm + scatter fused
    gemm_scatter<<<dim3(26 + sc_cols, gy), 256, 0, stream>>>(
        xb, WtA, xWb, xRoot, mtiles, ei, attr, cursor, epack, E);
    edge_csr<<<(N + 3) / 4, 256, 0, stream>>>(xWb, rowp, epack, xRoot, b1, nullptr, x1b, N);

    // layer 2: gemm only
    gemm_scatter<<<dim3(26, gy), 256, 0, stream>>>(
        x1b, WtB, xWb, xRoot, mtiles, nullptr, nullptr, nullptr, nullptr, E);
    edge_csr<<<(N + 3) / 4, 256, 0, stream>>>(xWb, rowp, epack, xRoot, b2, nullptr, x2b, N);

    // final: bf16 MFMA, fp32 out + fb
    final_mfma<<<mtiles, 256, 0, stream>>>(xb, x1b, x2b, fwT, fb, out, N);
}

// Round 3
// 385.740 us; speedup vs baseline: 1.3326x; 1.0549x over previous
//
#include <hip/hip_runtime.h>
#include <hip/hip_bf16.h>

// SplineCNN round 18: r17 barrier-free gemm was NEUTRAL (96us, same WRITE)
// => gemm pinned by traffic, not schedule. Byte audit of layer-1 gemm:
// ideal 186MB writes vs 219 measured + 38 fetch. Excess ~64-85MB == epack
// scatter RMW: 800k random 16B stores -> L2 write-allocate fetches 64B
// line + writes back 64B, region (12.8MB) >> 4MB/XCD L2 so most of the 4
// writes/line miss separately. Fixes:
//  (1) epack stores via __builtin_nontemporal_store (nt, no-allocate
//      streaming; HBM byte-masked writes need no fill). epack is read once
//      linearly later - caching never helped.
//  (2) xRoot fp32->bf16: -6.4MB write per gemm, -6.4MB read per edge.
// Everything else verbatim r17 (barrier-free per-wave LDS slices kept).

typedef short  bf16x8 __attribute__((ext_vector_type(8)));
typedef float  f32x4  __attribute__((ext_vector_type(4)));
typedef int    i32x4  __attribute__((ext_vector_type(4)));

__device__ __forceinline__ float bf2f(ushort u) {
    return __uint_as_float((uint)u << 16);
}
__device__ __forceinline__ ushort f2bf(float f) {   // round-to-nearest-even
    uint u = __float_as_uint(f);
    return (ushort)((u + 0x7FFF + ((u >> 16) & 1)) >> 16);
}

// ---------------- fused prep --------------------------------------------
__global__ __launch_bounds__(256) void prep(
    const float* __restrict__ x, ushort* __restrict__ xb, int nx,
    const float* __restrict__ W1, const float* __restrict__ r1, ushort* __restrict__ WtA,
    const float* __restrict__ W2, const float* __restrict__ r2, ushort* __restrict__ WtB,
    const float* __restrict__ fw, ushort* __restrict__ fwT,
    int* __restrict__ deg, int N)
{
    const int nw = 26 * 4096, nfw = 3 * 4096;
    int idx = blockIdx.x * 256 + threadIdx.x;
    if (idx < nx) { xb[idx] = f2bf(x[idx]); return; }
    idx -= nx;
    if (idx < nw) {
        int tile = idx >> 12, rem = idx & 4095, o = rem >> 6, i = rem & 63;
        WtA[idx] = f2bf(tile < 25 ? W1[tile * 4096 + i * 64 + o] : r1[i * 64 + o]);
        return;
    }
    idx -= nw;
    if (idx < nw) {
        int tile = idx >> 12, rem = idx & 4095, o = rem >> 6, i = rem & 63;
        WtB[idx] = f2bf(tile < 25 ? W2[tile * 4096 + i * 64 + o] : r2[i * 64 + o]);
        return;
    }
    idx -= nw;
    if (idx < nfw) {
        int t = idx >> 12, rem = idx & 4095, o = rem >> 6, k = rem & 63;
        fwT[idx] = f2bf(fw[(t * 64 + k) * 64 + o]);
        return;
    }
    idx -= nfw;
    if (idx < N) deg[idx] = 0;
}

// ---------------- CSR build ---------------------------------------------
__global__ __launch_bounds__(256) void hist_deg(
    const int* __restrict__ ei, int* __restrict__ deg, int E)
{
    int e = blockIdx.x * 256 + threadIdx.x;
    if (e < E) atomicAdd(&deg[ei[E + e]], 1);
}

__global__ __launch_bounds__(1024) void scan_block(
    const int* __restrict__ deg, int* __restrict__ inc,
    int* __restrict__ partial, int N)
{
    __shared__ int s[1024];
    int i = blockIdx.x * 1024 + threadIdx.x;
    int v = (i < N) ? deg[i] : 0;
    s[threadIdx.x] = v;
    __syncthreads();
    for (int off = 1; off < 1024; off <<= 1) {
        int t = (threadIdx.x >= off) ? s[threadIdx.x - off] : 0;
        __syncthreads();
        s[threadIdx.x] += t;
        __syncthreads();
    }
    if (i < N) inc[i] = s[threadIdx.x];
    if (threadIdx.x == 1023) partial[blockIdx.x] = s[1023];
}

__global__ void scan_partial(int* __restrict__ partial, int nb)  // nb <= 64
{
    __shared__ int s[64];
    int t = threadIdx.x;
    int v = (t < nb) ? partial[t] : 0;
    s[t] = v;
    __syncthreads();
    for (int off = 1; off < 64; off <<= 1) {
        int x = (t >= off) ? s[t - off] : 0;
        __syncthreads();
        s[t] += x;
        __syncthreads();
    }
    if (t < nb) partial[t] = s[t] - v;   // exclusive block offsets
}

__global__ __launch_bounds__(1024) void scan_finalize(
    const int* __restrict__ deg, const int* __restrict__ inc,
    const int* __restrict__ partial, int* __restrict__ row_ptr,
    int* __restrict__ cursor, int N)
{
    int i = blockIdx.x * 1024 + threadIdx.x;
    if (i >= N) return;
    int v = inc[i] + partial[blockIdx.x];
    row_ptr[i + 1] = v;
    cursor[i] = v - deg[i];
    if (i == 0) row_ptr[0] = 0;
}

// ---------------- fused MFMA GEMM + csr_scatter (barrier-free) ----------
__global__ __launch_bounds__(256) void gemm_scatter(
    const ushort* __restrict__ A, const ushort* __restrict__ Wt,
    ushort* __restrict__ xWb, ushort* __restrict__ xRoot, int mtiles,
    const int* __restrict__ ei, const float* __restrict__ attr,
    int* __restrict__ cursor, int4* __restrict__ epack, int E)
{
    __shared__ ushort Cs[4][16][72];   // per-wave slice, 144B rows
    const int bx = blockIdx.x;

    if (bx >= 26) {                 // ---- scatter path (layer 1 only) ----
        if (!ei) return;
        int e = ((bx - 26) * gridDim.y + blockIdx.y) * 256 + threadIdx.x;
        if (e >= E) return;
        int src = ei[e], dst = ei[E + e];
        float u = attr[2 * e] * 4.f;
        float v = attr[2 * e + 1] * 4.f;
        float lu = floorf(u), lv = floorf(v);
        float fu = u - lu, fv = v - lv;
        int iu = (int)lu;  iu = iu < 0 ? 0 : (iu > 4 ? 4 : iu);
        int iv = (int)lv;  iv = iv < 0 ? 0 : (iv > 4 ? 4 : iv);
        int iu1 = iu + 1 > 4 ? 4 : iu + 1;
        int iv1 = iv + 1 > 4 ? 4 : iv + 1;
        uint slots = (uint)(iu + 5 * iv) | ((uint)(iu + 5 * iv1) << 8) |
                     ((uint)(iu1 + 5 * iv) << 16) | ((uint)(iu1 + 5 * iv1) << 24);
        uint wlo = (uint)f2bf((1.f - fu) * (1.f - fv)) | ((uint)f2bf((1.f - fu) * fv) << 16);
        uint whi = (uint)f2bf(fu * (1.f - fv)) | ((uint)f2bf(fu * fv) << 16);
        int pos = atomicAdd(&cursor[dst], 1);
        i32x4 pk = {src * 3200, (int)slots, (int)wlo, (int)whi};
        __builtin_nontemporal_store(pk, (i32x4*)(epack + pos));   // nt: no write-allocate RMW
        return;
    }

    // ---- gemm path ----
    const int wave = threadIdx.x >> 6;
    const int lane = threadIdx.x & 63;
    const int l16 = lane & 15;
    const int half = lane >> 4;                 // 0..3
    ushort (*cw)[72] = Cs[wave];

    const ushort* btile = Wt + (size_t)bx * 4096;
    bf16x8 b0[4], b1[4];
    #pragma unroll
    for (int s = 0; s < 4; ++s) {
        const ushort* brow = btile + (size_t)(s * 16 + l16) * 64;
        b0[s] = *(const bf16x8*)(brow + half * 8);
        b1[s] = *(const bf16x8*)(brow + 32 + half * 8);
    }

    const int mt_base = blockIdx.y * 8;
    const int nit = (mtiles - mt_base) < 8 ? (mtiles - mt_base) : 8;

    // prefetch A for it=0
    const ushort* arow0 = A + (size_t)(mt_base * 64 + wave * 16 + l16) * 64;
    bf16x8 a0 = *(const bf16x8*)(arow0 + half * 8);
    bf16x8 a1 = *(const bf16x8*)(arow0 + 32 + half * 8);

    for (int it = 0; it < nit; ++it) {
        const int m0 = (mt_base + it) * 64;
        const int m_base = m0 + wave * 16;

        // issue next iteration's A loads BEFORE this iteration's stores
        bf16x8 na0, na1;
        if (it + 1 < nit) {
            const ushort* arow = A + (size_t)(m_base + 64 + l16) * 64;
            na0 = *(const bf16x8*)(arow + half * 8);
            na1 = *(const bf16x8*)(arow + 32 + half * 8);
        }

        f32x4 acc[4];
        #pragma unroll
        for (int s = 0; s < 4; ++s) {
            acc[s] = (f32x4){0.f, 0.f, 0.f, 0.f};
            acc[s] = __builtin_amdgcn_mfma_f32_16x16x32_bf16(a0, b0[s], acc[s], 0, 0, 0);
            acc[s] = __builtin_amdgcn_mfma_f32_16x16x32_bf16(a1, b1[s], acc[s], 0, 0, 0);
        }

        if (bx == 25) {   // root tile -> bf16 xRoot (padded ws, no guard)
            #pragma unroll
            for (int s = 0; s < 4; ++s)
                #pragma unroll
                for (int r = 0; r < 4; ++r)
                    xRoot[(size_t)(m_base + half * 4 + r) * 64 + s * 16 + l16] = f2bf(acc[s][r]);
        } else {
            // per-wave stage: bf16 fragment -> LDS slice (same-wave only)
            #pragma unroll
            for (int s = 0; s < 4; ++s)
                #pragma unroll
                for (int r = 0; r < 4; ++r)
                    cw[half * 4 + r][s * 16 + l16] = f2bf(acc[s][r]);
            // same-wave readback -> coalesced uint4 stores of our 16 rows
            #pragma unroll
            for (int i2 = 0; i2 < 2; ++i2) {
                int idx = i2 * 64 + lane;
                int row = idx >> 3, seg = idx & 7;
                uint4 v = *(const uint4*)&cw[row][seg * 8];
                *(uint4*)(xWb + (size_t)(m_base + row) * 1600 + bx * 64 + seg * 8) = v;
            }
        }
        a0 = na0; a1 = na1;
    }
}

// ---------------- edge pass: wave/dst, pipelined scalarized stream ------
__device__ __forceinline__ void gather4(
    const char* __restrict__ xwb, int lane, int rb, uint slots, ushort g[4])
{
    g[0] = *((const ushort*)(xwb + rb + ((slots & 255u) << 7)) + lane);
    g[1] = *((const ushort*)(xwb + rb + (((slots >> 8) & 255u) << 7)) + lane);
    g[2] = *((const ushort*)(xwb + rb + (((slots >> 16) & 255u) << 7)) + lane);
    g[3] = *((const ushort*)(xwb + rb + ((slots >> 24) << 7)) + lane);
}

__device__ __forceinline__ float consume4(const int4 d, const ushort g[4])
{
    float m = __uint_as_float((uint)d.z << 16) * bf2f(g[0]);
    m = fmaf(__uint_as_float((uint)d.z & 0xffff0000u), bf2f(g[1]), m);
    m = fmaf(__uint_as_float((uint)d.w << 16), bf2f(g[2]), m);
    m = fmaf(__uint_as_float((uint)d.w & 0xffff0000u), bf2f(g[3]), m);
    return m;
}

__global__ __launch_bounds__(256) void edge_csr(
    const ushort* __restrict__ xWb, const int* __restrict__ row_ptr,
    const int4* __restrict__ epack, const ushort* __restrict__ xRoot,
    const float* __restrict__ bias, float* __restrict__ outf,
    ushort* __restrict__ outb, int N)
{
    const int wv = __builtin_amdgcn_readfirstlane(threadIdx.x >> 6);
    const int d = blockIdx.x * 4 + wv;
    const int lane = threadIdx.x & 63;
    if (d >= N) return;
    const int e0 = __builtin_amdgcn_readfirstlane(row_ptr[d]);
    const int e1 = __builtin_amdgcn_readfirstlane(row_ptr[d + 1]);
    const char* xwb = (const char*)xWb;

    float vmax = -__builtin_inff();
    int e = e0;
    const int pairs = (e1 - e0) >> 1;
    if (pairs > 0) {
        int4 dA = epack[e], dB = epack[e + 1];
        ushort gA[4], gB[4];
        gather4(xwb, lane, dA.x, (uint)dA.y, gA);
        gather4(xwb, lane, dB.x, (uint)dB.y, gB);
        for (int p = 1; p < pairs; ++p) {
            int4 nA = epack[e + 2 * p], nB = epack[e + 2 * p + 1];
            ushort hA[4], hB[4];
            gather4(xwb, lane, nA.x, (uint)nA.y, hA);
            gather4(xwb, lane, nB.x, (uint)nB.y, hB);
            vmax = fmaxf(vmax, fmaxf(consume4(dA, gA), consume4(dB, gB)));
            #pragma unroll
            for (int i = 0; i < 4; ++i) { gA[i] = hA[i]; gB[i] = hB[i]; }
            dA = nA; dB = nB;
        }
        vmax = fmaxf(vmax, fmaxf(consume4(dA, gA), consume4(dB, gB)));
        e += pairs * 2;
    }
    if (e < e1) {   // odd remainder
        int4 dA = epack[e];
        ushort gA[4];
        gather4(xwb, lane, dA.x, (uint)dA.y, gA);
        vmax = fmaxf(vmax, consume4(dA, gA));
    }
    if (e1 == e0) vmax = 0.f;          // segment_max(-inf) -> 0
    float val = vmax + bf2f(xRoot[(size_t)d * 64 + lane]) + bias[lane];
    val = fmaxf(val, 0.f);
    if (outf) outf[(size_t)d * 64 + lane] = val;
    if (outb) outb[(size_t)d * 64 + lane] = f2bf(val);
}

// ---------------- final: out = [xb|x1b|x2b] @ fwT + fb (bf16 MFMA) ------
__global__ __launch_bounds__(256) void final_mfma(
    const ushort* __restrict__ xb, const ushort* __restrict__ x1b,
    const ushort* __restrict__ x2b, const ushort* __restrict__ fwT,
    const float* __restrict__ fb, float* __restrict__ out, int M)
{
    const int wave = threadIdx.x >> 6;
    const int lane = threadIdx.x & 63;
    const int l16 = lane & 15;
    const int half = lane >> 4;
    const int m_base = blockIdx.x * 64 + wave * 16;
    const ushort* srcs[3] = {xb, x1b, x2b};

    f32x4 acc[4];
    #pragma unroll
    for (int s = 0; s < 4; ++s) acc[s] = (f32x4){0.f, 0.f, 0.f, 0.f};

    #pragma unroll
    for (int t = 0; t < 3; ++t) {
        const ushort* arow = srcs[t] + (size_t)(m_base + l16) * 64;
        bf16x8 a0 = *(const bf16x8*)(arow + half * 8);
        bf16x8 a1 = *(const bf16x8*)(arow + 32 + half * 8);
        const ushort* btile = fwT + (size_t)t * 4096;
        #pragma unroll
        for (int s = 0; s < 4; ++s) {
            const ushort* brow = btile + (size_t)(s * 16 + l16) * 64;
            bf16x8 b0 = *(const bf16x8*)(brow + half * 8);
            bf16x8 b1 = *(const bf16x8*)(brow + 32 + half * 8);
            acc[s] = __builtin_amdgcn_mfma_f32_16x16x32_bf16(a0, b0, acc[s], 0, 0, 0);
            acc[s] = __builtin_amdgcn_mfma_f32_16x16x32_bf16(a1, b1, acc[s], 0, 0, 0);
        }
    }

    #pragma unroll
    for (int s = 0; s < 4; ++s) {
        int o = s * 16 + l16;
        float b = fb[o];
        #pragma unroll
        for (int r = 0; r < 4; ++r) {
            int m = m_base + half * 4 + r;
            if (m < M) out[(size_t)m * 64 + o] = acc[s][r] + b;
        }
    }
}

extern "C" void kernel_launch(void* const* d_in, const int* in_sizes, int n_in,
                              void* d_out, int out_size, void* d_ws, size_t ws_size,
                              hipStream_t stream)
{
    const float* x    = (const float*)d_in[0];
    const int*   ei   = (const int*)d_in[1];
    const float* attr = (const float*)d_in[2];
    const float* W1   = (const float*)d_in[3];
    const float* r1   = (const float*)d_in[4];
    const float* b1   = (const float*)d_in[5];
    const float* W2   = (const float*)d_in[6];
    const float* r2   = (const float*)d_in[7];
    const float* b2   = (const float*)d_in[8];
    const float* fw   = (const float*)d_in[9];
    const float* fb   = (const float*)d_in[10];
    float* out = (float*)d_out;

    const int N = in_sizes[0] / 64;
    const int E = in_sizes[1] / 2;
    const int mtiles = (N + 63) / 64;
    const int Npad = mtiles * 64;

    // workspace carve (~210 MB; ws_size >= 358 MB per round-2 evidence)
    char* p = (char*)d_ws;
    auto alloc = [&](size_t bytes) { void* q = p; p += (bytes + 255) & ~(size_t)255; return q; };
    int4*   epack  = (int4*)alloc((size_t)E * 16);
    ushort* xRoot  = (ushort*)alloc((size_t)Npad * 64 * 2);
    ushort* xWb    = (ushort*)alloc((size_t)Npad * 1600 * 2);
    ushort* xb     = (ushort*)alloc((size_t)Npad * 64 * 2);
    ushort* x1b    = (ushort*)alloc((size_t)Npad * 64 * 2);
    ushort* x2b    = (ushort*)alloc((size_t)Npad * 64 * 2);
    ushort* WtA    = (ushort*)alloc((size_t)26 * 4096 * 2);
    ushort* WtB    = (ushort*)alloc((size_t)26 * 4096 * 2);
    ushort* fwT    = (ushort*)alloc((size_t)3 * 4096 * 2);
    int*    deg    = (int*)alloc((size_t)N * 4);
    int*    cursor = (int*)alloc((size_t)N * 4);
    int*    rowp   = (int*)alloc((size_t)(N + 1) * 4);
    int*    tmpinc = (int*)alloc((size_t)N * 4);
    int*    part   = (int*)alloc(64 * 4);

    const int nb = (N + 1023) / 1024;   // <= 64 for N <= 65536

    // fused prep: xb, WtA, WtB, fwT, zero deg
    const int nprep = N * 64 + 2 * 26 * 4096 + 3 * 4096 + N;
    prep<<<(nprep + 255) / 256, 256, 0, stream>>>(
        x, xb, N * 64, W1, r1, WtA, W2, r2, WtB, fw, fwT, deg, N);

    // CSR scan chain (scatter fused into layer-1 gemm)
    hist_deg<<<(E + 255) / 256, 256, 0, stream>>>(ei, deg, E);
    scan_block<<<nb, 1024, 0, stream>>>(deg, tmpinc, part, N);
    scan_partial<<<1, 64, 0, stream>>>(part, nb);
    scan_finalize<<<nb, 1024, 0, stream>>>(deg, tmpinc, part, rowp, cursor, N);

    const int gy = (mtiles + 7) / 8;
    const int sc_blocks = (E + 255) / 256;
    const int sc_cols = (sc_blocks + gy - 1) / gy;

    // layer 1: gemm + scatter fused
    gemm_scatter<<<dim3(26 + sc_cols, gy), 256, 0, stream>>>(
        xb, WtA, xWb, xRoot, mtiles, ei, attr, cursor, epack, E);
    edge_csr<<<(N + 3) / 4, 256, 0, stream>>>(xWb, rowp, epack, xRoot, b1, nullptr, x1b, N);

    // layer 2: gemm only
    gemm_scatter<<<dim3(26, gy), 256, 0, stream>>>(
        x1b, WtB, xWb, xRoot, mtiles, nullptr, nullptr, nullptr, nullptr, E);
    edge_csr<<<(N + 3) / 4, 256, 0, stream>>>(xWb, rowp, epack, xRoot, b2, nullptr, x2b, N);

    // final: bf16 MFMA, fp32 out + fb
    final_mfma<<<mtiles, 256, 0, stream>>>(xb, x1b, x2b, fwT, fb, out, N);
}